// Round 9
// baseline (355.628 us; speedup 1.0000x reference)
//
#include <hip/hip_runtime.h>

#define BATCH   1024
#define GROUPS  512
#define OUT_DIM 64
#define ROW_WORDS 68

typedef float f32x4 __attribute__((ext_vector_type(4)));

// ============================================================================
// DIAGNOSTIC ROUND. Real kernel (r5-best, unchanged) runs first -> output
// correct. Then three probe kernels write ~640 MB each into d_ws so they
// OUTRANK the ~86us harness fills and expose their counters in the top-5:
//   A: linear stream writes (control; expect ~6.4 TB/s)
//   B: 256B chunks @ 128KiB frame stride = real kernel's store pattern,
//      same inst count/volume as A  -> isolates store-pattern penalty
//   C: real algorithm x5 reps with LINEAR stores -> isolates read/compute/LDS
// Decision rule in journal. Probes guarded by ws_size >= 128 MiB.
// ============================================================================

__global__ __launch_bounds__(256) void hoact_kernel(
    const float4* __restrict__ X4,
    const float4* __restrict__ P4,
    float4*       __restrict__ O4)
{
    __shared__ float tbl[16 * ROW_WORDS];

    const int xcd   = blockIdx.x & 7;
    const int idx   = blockIdx.x >> 3;
    const int g     = xcd * 64 + (idx & 63);
    const int chunk = idx >> 6;
    const int b0    = chunk * 256;
    const int tid   = threadIdx.x;

    {
        const float4 v = P4[g * 256 + tid];
        const int row = tid >> 4, c4 = tid & 15;
        *(float4*)&tbl[row * ROW_WORDS + c4 * 4] = v;
    }

    const int t       = tid & 7;
    const int bl_base = tid >> 3;

    float4 xv[8];
#pragma unroll
    for (int p = 0; p < 8; ++p) {
        const int b = b0 + p * 32 + bl_base;
        xv[p] = X4[b * GROUPS + g];
    }

    __syncthreads();

    const f32x4 p0a = *(const f32x4*)&tbl[15 * ROW_WORDS + t * 4];
    const f32x4 p0b = *(const f32x4*)&tbl[15 * ROW_WORDS + (t + 8) * 4];

#pragma unroll
    for (int p = 0; p < 8; ++p) {
        const int b = b0 + p * 32 + bl_base;
        const float4 x = xv[p];

        float v0 = __uint_as_float((__float_as_uint(x.x) & ~3u) | 0u);
        float v1 = __uint_as_float((__float_as_uint(x.y) & ~3u) | 1u);
        float v2 = __uint_as_float((__float_as_uint(x.z) & ~3u) | 2u);
        float v3 = __uint_as_float((__float_as_uint(x.w) & ~3u) | 3u);

#define CSWAP(a, b_)                                 \
        {                                            \
            const float lo = fminf((a), (b_));       \
            const float hi = fmaxf((a), (b_));       \
            (a) = lo; (b_) = hi;                     \
        }
        CSWAP(v0, v1);
        CSWAP(v2, v3);
        CSWAP(v0, v2);
        CSWAP(v1, v3);
        CSWAP(v1, v2);
#undef CSWAP

        const int i1 = __float_as_uint(v1) & 3;
        const int i2 = __float_as_uint(v2) & 3;
        const int i3 = __float_as_uint(v3) & 3;

        const float c0 = v0;
        const float c1 = v1 - v0;
        const float c2 = v2 - v1;
        const float c3 = v3 - v2;

        const int e3 = 1 << i3;
        const int e2 = e3 + (1 << i2);
        const int e1 = e2 + (1 << i1);

        const f32x4 p1a = *(const f32x4*)&tbl[e1 * ROW_WORDS + t * 4];
        const f32x4 p1b = *(const f32x4*)&tbl[e1 * ROW_WORDS + (t + 8) * 4];
        const f32x4 p2a = *(const f32x4*)&tbl[e2 * ROW_WORDS + t * 4];
        const f32x4 p2b = *(const f32x4*)&tbl[e2 * ROW_WORDS + (t + 8) * 4];
        const f32x4 p3a = *(const f32x4*)&tbl[e3 * ROW_WORDS + t * 4];
        const f32x4 p3b = *(const f32x4*)&tbl[e3 * ROW_WORDS + (t + 8) * 4];

        float4 oa, ob;
        oa.x = c0 * p0a.x + c1 * p1a.x + c2 * p2a.x + c3 * p3a.x;
        oa.y = c0 * p0a.y + c1 * p1a.y + c2 * p2a.y + c3 * p3a.y;
        oa.z = c0 * p0a.z + c1 * p1a.z + c2 * p2a.z + c3 * p3a.z;
        oa.w = c0 * p0a.w + c1 * p1a.w + c2 * p2a.w + c3 * p3a.w;
        ob.x = c0 * p0b.x + c1 * p1b.x + c2 * p2b.x + c3 * p3b.x;
        ob.y = c0 * p0b.y + c1 * p1b.y + c2 * p2b.y + c3 * p3b.y;
        ob.z = c0 * p0b.z + c1 * p1b.z + c2 * p2b.z + c3 * p3b.z;
        ob.w = c0 * p0b.w + c1 * p1b.w + c2 * p2b.w + c3 * p3b.w;

        const int o_idx = b * (GROUPS * 16) + g * 16 + t;
        O4[o_idx]     = oa;
        O4[o_idx + 8] = ob;
    }
}

// ---------------- Probe A: linear stream writes, 640 MB ----------------
#define REGION_MASK ((1u << 23) - 1u)   // 8M float4 = 128 MiB window
#define PROBE_ITERS 80                  // 80 x 8 MiB = 640 MB

__global__ __launch_bounds__(256) void probe_linear(float4* __restrict__ ws)
{
    const unsigned base = blockIdx.x * 256u + threadIdx.x;
    const float4 val = make_float4(1.0f, 2.0f, 3.0f, (float)base);
    for (unsigned it = 0; it < PROBE_ITERS; ++it) {
        const unsigned idx = (it * (2048u * 256u) + base) & REGION_MASK;
        ws[idx] = val;
    }
}

// ---- Probe B: 256B chunks at 128KiB frame stride (real store pattern) ----
// chunk c: frame b' = c & 1023 (128 KiB apart), column g' = (c>>10) & 511.
// Per wave-inst: 4 chunks = 4 x 256B scattered 128KiB apart — exactly the
// real kernel's store shape. Same loop count / volume as probe A.
__global__ __launch_bounds__(256) void probe_strided(float4* __restrict__ ws)
{
    const unsigned tid   = threadIdx.x;
    const unsigned c4    = tid & 15u;
    const unsigned slot  = blockIdx.x * 16u + (tid >> 4);   // 32768 slots/iter
    const float4 val = make_float4(4.0f, 5.0f, 6.0f, (float)slot);
    for (unsigned it = 0; it < PROBE_ITERS; ++it) {
        const unsigned c  = it * 32768u + slot;
        const unsigned bp = c & 1023u;
        const unsigned gp = (c >> 10) & 511u;
        ws[bp * 8192u + gp * 16u + c4] = val;
    }
}

// ---- Probe C: real algorithm x5 reps, LINEAR stores into ws ----
#define C_REPS 5
__global__ __launch_bounds__(256) void probe_compute(
    const float4* __restrict__ X4,
    const float4* __restrict__ P4,
    float4*       __restrict__ ws)
{
    __shared__ float tbl[16 * ROW_WORDS];

    const int xcd   = blockIdx.x & 7;
    const int idx   = blockIdx.x >> 3;
    const int g     = xcd * 64 + (idx & 63);
    const int chunk = idx >> 6;
    const int b0    = chunk * 256;
    const int tid   = threadIdx.x;

    {
        const float4 v = P4[g * 256 + tid];
        const int row = tid >> 4, c4 = tid & 15;
        *(float4*)&tbl[row * ROW_WORDS + c4 * 4] = v;
    }

    const int t       = tid & 7;
    const int bl_base = tid >> 3;
    const unsigned lin = (blockIdx.x * 256u + tid) * 2u;   // 2 float4/thread

    __syncthreads();

    const f32x4 p0a = *(const f32x4*)&tbl[15 * ROW_WORDS + t * 4];
    const f32x4 p0b = *(const f32x4*)&tbl[15 * ROW_WORDS + (t + 8) * 4];

    for (int rep = 0; rep < C_REPS; ++rep) {
        float4 xv[8];
#pragma unroll
        for (int p = 0; p < 8; ++p)
            xv[p] = X4[(b0 + p * 32 + bl_base) * GROUPS + g];

#pragma unroll
        for (int p = 0; p < 8; ++p) {
            const float4 x = xv[p];

            float v0 = __uint_as_float((__float_as_uint(x.x) & ~3u) | 0u);
            float v1 = __uint_as_float((__float_as_uint(x.y) & ~3u) | 1u);
            float v2 = __uint_as_float((__float_as_uint(x.z) & ~3u) | 2u);
            float v3 = __uint_as_float((__float_as_uint(x.w) & ~3u) | 3u);

#define CSWAP(a, b_)                                 \
            {                                        \
                const float lo = fminf((a), (b_));   \
                const float hi = fmaxf((a), (b_));   \
                (a) = lo; (b_) = hi;                 \
            }
            CSWAP(v0, v1);
            CSWAP(v2, v3);
            CSWAP(v0, v2);
            CSWAP(v1, v3);
            CSWAP(v1, v2);
#undef CSWAP

            const int i1 = __float_as_uint(v1) & 3;
            const int i2 = __float_as_uint(v2) & 3;
            const int i3 = __float_as_uint(v3) & 3;

            const float c0 = v0;
            const float c1 = v1 - v0;
            const float c2 = v2 - v1;
            const float c3 = v3 - v2;

            const int e3 = 1 << i3;
            const int e2 = e3 + (1 << i2);
            const int e1 = e2 + (1 << i1);

            const f32x4 p1a = *(const f32x4*)&tbl[e1 * ROW_WORDS + t * 4];
            const f32x4 p1b = *(const f32x4*)&tbl[e1 * ROW_WORDS + (t + 8) * 4];
            const f32x4 p2a = *(const f32x4*)&tbl[e2 * ROW_WORDS + t * 4];
            const f32x4 p2b = *(const f32x4*)&tbl[e2 * ROW_WORDS + (t + 8) * 4];
            const f32x4 p3a = *(const f32x4*)&tbl[e3 * ROW_WORDS + t * 4];
            const f32x4 p3b = *(const f32x4*)&tbl[e3 * ROW_WORDS + (t + 8) * 4];

            float4 oa, ob;
            oa.x = c0 * p0a.x + c1 * p1a.x + c2 * p2a.x + c3 * p3a.x;
            oa.y = c0 * p0a.y + c1 * p1a.y + c2 * p2a.y + c3 * p3a.y;
            oa.z = c0 * p0a.z + c1 * p1a.z + c2 * p2a.z + c3 * p3a.z;
            oa.w = c0 * p0a.w + c1 * p1a.w + c2 * p2a.w + c3 * p3a.w;
            ob.x = c0 * p0b.x + c1 * p1b.x + c2 * p2b.x + c3 * p3b.x;
            ob.y = c0 * p0b.y + c1 * p1b.y + c2 * p2b.y + c3 * p3b.y;
            ob.z = c0 * p0b.z + c1 * p1b.z + c2 * p2b.z + c3 * p3b.z;
            ob.w = c0 * p0b.w + c1 * p1b.w + c2 * p2b.w + c3 * p3b.w;

            // linear ws stores: slot = (rep*8+p)&7 -> 8 x 16 MiB = 128 MiB
            const unsigned base = (((unsigned)(rep * 8 + p) & 7u) << 20);
            ws[base + lin]      = oa;
            ws[base + lin + 1u] = ob;
        }
    }
}

extern "C" void kernel_launch(void* const* d_in, const int* in_sizes, int n_in,
                              void* d_out, int out_size, void* d_ws, size_t ws_size,
                              hipStream_t stream) {
    const float4* X4 = (const float4*)d_in[0];
    const float4* P4 = (const float4*)d_in[1];
    float4*       O4 = (float4*)d_out;

    // real kernel first: output stays correct
    hipLaunchKernelGGL(hoact_kernel, dim3(2048), dim3(256), 0, stream,
                       X4, P4, O4);

    // diagnostic probes into workspace (need 128 MiB window)
    if (ws_size >= (size_t)134217728 && d_ws != nullptr) {
        float4* W = (float4*)d_ws;
        hipLaunchKernelGGL(probe_linear,  dim3(2048), dim3(256), 0, stream, W);
        hipLaunchKernelGGL(probe_strided, dim3(2048), dim3(256), 0, stream, W);
        hipLaunchKernelGGL(probe_compute, dim3(2048), dim3(256), 0, stream,
                           X4, P4, W);
    }
}

// Round 10
// 251.391 us; speedup vs baseline: 1.4146x; 1.4146x over previous
//
#include <hip/hip_runtime.h>

#define BATCH   1024
#define GROUPS  512
#define ROW_WORDS 68
#define REPS    4

typedef float f32x4 __attribute__((ext_vector_type(4)));

// ============================================================================
// DIAGNOSTIC ROUND 2 (decisive d_out-vs-ws discrimination + first-ever real
// counters). Same r5-best algorithm, templated on TAG so the two dispatches
// get distinct kernel names in rocprof:
//   hoact_rep<0> -> d_out : 4 idempotent reps (identical values to identical
//                           addresses; output remains correct)
//   hoact_rep<1> -> d_ws  : same 4 reps, same scatter addresses, ws base
// 4 reps puts BOTH dispatches (~110-250 us) above the ~86 us harness fills,
// so the top-5 finally shows VALUBusy / LDS-conflict / FETCH / WRITE /
// Occupancy for the real algorithm + store pattern, split by destination.
// asm memory clobber between reps prevents dead-store elimination of the
// earlier idempotent writes.
// Decision rule (pre-committed): D1≈D2 -> d_out exonerated, read counters
// (VALU-bound / LDS-bound / latency-bound branches). D1>=1.3x D2 -> d_out
// write path is the structural cost.
// ============================================================================

template<int TAG>
__global__ __launch_bounds__(256) void hoact_rep(
    const float4* __restrict__ X4,   // [B*G]
    const float4* __restrict__ P4,   // [G*256]
    float4*       __restrict__ dst)  // [B*G*16] layout (d_out or ws mirror)
{
    __shared__ float tbl[16 * ROW_WORDS];

    const int xcd   = blockIdx.x & 7;
    const int idx   = blockIdx.x >> 3;
    const int g     = xcd * 64 + (idx & 63);
    const int chunk = idx >> 6;
    const int b0    = chunk * 256;
    const int tid   = threadIdx.x;

    {
        const float4 v = P4[g * 256 + tid];
        const int row = tid >> 4, c4 = tid & 15;
        *(float4*)&tbl[row * ROW_WORDS + c4 * 4] = v;
    }

    const int t       = tid & 7;
    const int bl_base = tid >> 3;

    __syncthreads();

    const f32x4 p0a = *(const f32x4*)&tbl[15 * ROW_WORDS + t * 4];
    const f32x4 p0b = *(const f32x4*)&tbl[15 * ROW_WORDS + (t + 8) * 4];

    for (int rep = 0; rep < REPS; ++rep) {
        float4 xv[8];
#pragma unroll
        for (int p = 0; p < 8; ++p)
            xv[p] = X4[(b0 + p * 32 + bl_base) * GROUPS + g];

#pragma unroll
        for (int p = 0; p < 8; ++p) {
            const int b = b0 + p * 32 + bl_base;
            const float4 x = xv[p];

            float v0 = __uint_as_float((__float_as_uint(x.x) & ~3u) | 0u);
            float v1 = __uint_as_float((__float_as_uint(x.y) & ~3u) | 1u);
            float v2 = __uint_as_float((__float_as_uint(x.z) & ~3u) | 2u);
            float v3 = __uint_as_float((__float_as_uint(x.w) & ~3u) | 3u);

#define CSWAP(a, b_)                                 \
            {                                        \
                const float lo = fminf((a), (b_));   \
                const float hi = fmaxf((a), (b_));   \
                (a) = lo; (b_) = hi;                 \
            }
            CSWAP(v0, v1);
            CSWAP(v2, v3);
            CSWAP(v0, v2);
            CSWAP(v1, v3);
            CSWAP(v1, v2);
#undef CSWAP

            const int i1 = __float_as_uint(v1) & 3;
            const int i2 = __float_as_uint(v2) & 3;
            const int i3 = __float_as_uint(v3) & 3;

            const float c0 = v0;
            const float c1 = v1 - v0;
            const float c2 = v2 - v1;
            const float c3 = v3 - v2;

            const int e3 = 1 << i3;
            const int e2 = e3 + (1 << i2);
            const int e1 = e2 + (1 << i1);

            const f32x4 p1a = *(const f32x4*)&tbl[e1 * ROW_WORDS + t * 4];
            const f32x4 p1b = *(const f32x4*)&tbl[e1 * ROW_WORDS + (t + 8) * 4];
            const f32x4 p2a = *(const f32x4*)&tbl[e2 * ROW_WORDS + t * 4];
            const f32x4 p2b = *(const f32x4*)&tbl[e2 * ROW_WORDS + (t + 8) * 4];
            const f32x4 p3a = *(const f32x4*)&tbl[e3 * ROW_WORDS + t * 4];
            const f32x4 p3b = *(const f32x4*)&tbl[e3 * ROW_WORDS + (t + 8) * 4];

            float4 oa, ob;
            oa.x = c0 * p0a.x + c1 * p1a.x + c2 * p2a.x + c3 * p3a.x;
            oa.y = c0 * p0a.y + c1 * p1a.y + c2 * p2a.y + c3 * p3a.y;
            oa.z = c0 * p0a.z + c1 * p1a.z + c2 * p2a.z + c3 * p3a.z;
            oa.w = c0 * p0a.w + c1 * p1a.w + c2 * p2a.w + c3 * p3a.w;
            ob.x = c0 * p0b.x + c1 * p1b.x + c2 * p2b.x + c3 * p3b.x;
            ob.y = c0 * p0b.y + c1 * p1b.y + c2 * p2b.y + c3 * p3b.y;
            ob.z = c0 * p0b.z + c1 * p1b.z + c2 * p2b.z + c3 * p3b.z;
            ob.w = c0 * p0b.w + c1 * p1b.w + c2 * p2b.w + c3 * p3b.w;

            const int o_idx = b * (GROUPS * 16) + g * 16 + t;
            dst[o_idx]     = oa;
            dst[o_idx + 8] = ob;
        }
        // keep every rep's stores (block dead-store elimination across reps)
        __asm__ volatile("" ::: "memory");
    }
}

extern "C" void kernel_launch(void* const* d_in, const int* in_sizes, int n_in,
                              void* d_out, int out_size, void* d_ws, size_t ws_size,
                              hipStream_t stream) {
    const float4* X4 = (const float4*)d_in[0];   // X: [1024, 512, 4] fp32
    const float4* P4 = (const float4*)d_in[1];   // params: [512, 16, 64] fp32
    float4*       O4 = (float4*)d_out;           // out: [1024, 512, 64] fp32

    // D1: real output (4 idempotent reps -> correct result, visible counters)
    hipLaunchKernelGGL((hoact_rep<0>), dim3(2048), dim3(256), 0, stream,
                       X4, P4, O4);

    // D2: identical work, identical addresses, workspace base (needs 128 MiB;
    // r9 proved ws_size >= 134217728 on this harness)
    if (ws_size >= (size_t)134217728 && d_ws != nullptr) {
        hipLaunchKernelGGL((hoact_rep<1>), dim3(2048), dim3(256), 0, stream,
                           X4, P4, (float4*)d_ws);
    }
}

// Round 11
// 148.490 us; speedup vs baseline: 2.3950x; 1.6930x over previous
//
#include <hip/hip_runtime.h>

#define BATCH   1024
#define GROUPS  512

typedef float f32x4 __attribute__((ext_vector_type(4)));

// r11: long-store-stream restructure. Evidence (r9/r10 probes): store scatter
// pattern, compute+LDS+reads, and d_out destination each hit write roofline
// (>=6.2 TB/s) in isolation AND composed -- but only when each wave streams
// ~64 float4 stores (r10's 4-rep dispatch; harness fill: 9.5% occupancy, long
// streams, 6.2 TB/s). r5's 16-store-per-thread waves ran at 2.2 TB/s.
// => control stream length: 512 blocks x 256 thr, block = one group g,
// sweep ALL 1024 batches in 32 passes = 64 float4 stores/thread (4x r5).
//
// - g map: g = (blockIdx&7)*64 + (blockIdx>>3): bijective; XCD k owns the
//   contiguous g-range [64k,64k+64) so the 4 groups sharing each 64 B X-line
//   hit the same XCD's L2 (X HBM ~8 MB); params staged once per g = 2 MB
//   global minimum.
// - LDS linear [16][64]: each 8-lane t-group's ds_read_b128 covers 32
//   consecutive words; 8 groups/wave = every bank exactly 8x = the wave64
//   minimum -> conflict-free for any data-dependent row. No padding.
// - X pipelined 4 deep, rolling xv[p&3], slot read into x BEFORE refill
//   (r7-audited pattern); #pragma unroll 4 keeps indices compile-time
//   (rule #20: no runtime-indexed register arrays).
__global__ __launch_bounds__(256) void hoact_kernel(
    const float4* __restrict__ X4,   // [B*G]       (4 f32 -> one float4)
    const float4* __restrict__ P4,   // [G*256]     (16 rows x 16 float4)
    float4*       __restrict__ O4)   // [B*G*16]
{
    __shared__ float tbl[16 * 64];   // 4 KiB, linear == params layout

    const int g   = (blockIdx.x & 7) * 64 + (blockIdx.x >> 3);  // 0..511
    const int tid = threadIdx.x;     // 0..255

    // ---- stage params[g] once: 256 threads x 1 float4, coalesced 4 KiB ----
    {
        const float4 v = P4[g * 256 + tid];
        *(float4*)&tbl[tid << 2] = v;            // ds_write_b128, linear
    }

    const int t  = tid & 7;          // float4 column within D=64 (t and t+8)
    const int bl = tid >> 3;         // 0..31: batch lane within a pass

    // ---- prefetch X for passes 0..3 (rolling 4-deep pipeline) ----
    float4 xv[4];
#pragma unroll
    for (int p = 0; p < 4; ++p)
        xv[p] = X4[(p * 32 + bl) * GROUPS + g];  // 8 lanes broadcast one addr

    __syncthreads();

    // ---- pass-invariant row 15 (e0 == 15 for every input) ----
    const f32x4 p0a = *(const f32x4*)&tbl[15 * 64 + t * 4];
    const f32x4 p0b = *(const f32x4*)&tbl[15 * 64 + (t + 8) * 4];

#pragma unroll 4
    for (int p = 0; p < 32; ++p) {
        const int b = p * 32 + bl;
        const float4 x = xv[p & 3];

        // refill slot 4 passes ahead (slot already consumed into x)
        if (p < 28)
            xv[p & 3] = X4[((p + 4) * 32 + bl) * GROUPS + g];

        // pack 2-bit source index into mantissa LSBs (<=3 ULP, harmless);
        // sort via fmin/fmax network; ties -> zero gap coef.
        float v0 = __uint_as_float((__float_as_uint(x.x) & ~3u) | 0u);
        float v1 = __uint_as_float((__float_as_uint(x.y) & ~3u) | 1u);
        float v2 = __uint_as_float((__float_as_uint(x.z) & ~3u) | 2u);
        float v3 = __uint_as_float((__float_as_uint(x.w) & ~3u) | 3u);

#define CSWAP(a, b_)                                 \
        {                                            \
            const float lo = fminf((a), (b_));       \
            const float hi = fmaxf((a), (b_));       \
            (a) = lo; (b_) = hi;                     \
        }
        CSWAP(v0, v1);
        CSWAP(v2, v3);
        CSWAP(v0, v2);
        CSWAP(v1, v3);
        CSWAP(v1, v2);
#undef CSWAP

        const int i1 = __float_as_uint(v1) & 3;
        const int i2 = __float_as_uint(v2) & 3;
        const int i3 = __float_as_uint(v3) & 3;

        const float c0 = v0;
        const float c1 = v1 - v0;
        const float c2 = v2 - v1;
        const float c3 = v3 - v2;

        const int e3 = 1 << i3;
        const int e2 = e3 + (1 << i2);
        const int e1 = e2 + (1 << i1);
        // e0 == 15 always (hoisted above)

        const f32x4 p1a = *(const f32x4*)&tbl[(e1 << 6) + t * 4];
        const f32x4 p1b = *(const f32x4*)&tbl[(e1 << 6) + (t + 8) * 4];
        const f32x4 p2a = *(const f32x4*)&tbl[(e2 << 6) + t * 4];
        const f32x4 p2b = *(const f32x4*)&tbl[(e2 << 6) + (t + 8) * 4];
        const f32x4 p3a = *(const f32x4*)&tbl[(e3 << 6) + t * 4];
        const f32x4 p3b = *(const f32x4*)&tbl[(e3 << 6) + (t + 8) * 4];

        float4 oa, ob;
        oa.x = c0 * p0a.x + c1 * p1a.x + c2 * p2a.x + c3 * p3a.x;
        oa.y = c0 * p0a.y + c1 * p1a.y + c2 * p2a.y + c3 * p3a.y;
        oa.z = c0 * p0a.z + c1 * p1a.z + c2 * p2a.z + c3 * p3a.z;
        oa.w = c0 * p0a.w + c1 * p1a.w + c2 * p2a.w + c3 * p3a.w;
        ob.x = c0 * p0b.x + c1 * p1b.x + c2 * p2b.x + c3 * p3b.x;
        ob.y = c0 * p0b.y + c1 * p1b.y + c2 * p2b.y + c3 * p3b.y;
        ob.z = c0 * p0b.z + c1 * p1b.z + c2 * p2b.z + c3 * p3b.z;
        ob.w = c0 * p0b.w + c1 * p1b.w + c2 * p2b.w + c3 * p3b.w;

        // out[b][g][:]: per wave 8 rows x 2 x 128 B; pattern proven at
        // roofline by probe B / r10. Plain stores.
        const int o_idx = b * (GROUPS * 16) + g * 16 + t;
        O4[o_idx]     = oa;
        O4[o_idx + 8] = ob;
    }
}

extern "C" void kernel_launch(void* const* d_in, const int* in_sizes, int n_in,
                              void* d_out, int out_size, void* d_ws, size_t ws_size,
                              hipStream_t stream) {
    const float4* X4 = (const float4*)d_in[0];   // X: [1024, 512, 4] fp32
    const float4* P4 = (const float4*)d_in[1];   // params: [512, 16, 64] fp32
    float4*       O4 = (float4*)d_out;           // out: [1024, 512, 64] fp32

    const int grid = 512;                        // one block per group
    hipLaunchKernelGGL(hoact_kernel, dim3(grid), dim3(256), 0, stream,
                       X4, P4, O4);
}